// Round 6
// baseline (715.206 us; speedup 1.0000x reference)
//
#include <hip/hip_runtime.h>
#include <hip/hip_bf16.h>

typedef unsigned short u16;
typedef unsigned long long u64;
typedef __attribute__((ext_vector_type(4))) short short4v;
typedef __attribute__((ext_vector_type(8))) short short8;
typedef __attribute__((ext_vector_type(4))) float floatx4;

__device__ __forceinline__ u16 f2bf(float f) {
    union { float f; unsigned u; } v; v.f = f;
    unsigned r = v.u + 0x7FFF + ((v.u >> 16) & 1);
    return (u16)(r >> 16);
}

// ---------------------------------------------------------------------------
// Wcat stack: 7 slabs [B_0..B_5, selfW^T], K = 3584, fragment layout validated
// element (k,n) at: (k>>5)*16384 + (n>>4)*512 + ((k>>3)&3)*128 + (n&15)*8 + (k&7)
__global__ void k_wcat(const float* __restrict__ basis, const float* __restrict__ selfW,
                       u16* __restrict__ wf) {
    int bi = blockIdx.x, t = threadIdx.x;
    int kr = t >> 7;             // 0..1
    int nb = (t & 127) * 4;      // n base
    for (int it = 0; it < 4; ++it) {
        int k = bi * 8 + it * 2 + kr;     // 0..3583 over grid 448
        float v0, v1, v2, v3;
        if (k < 3072) {
            int q = k >> 9, h = k & 511;
            const float4 bz = *(const float4*)(basis + ((size_t)(q * 512 + h)) * 512 + nb);
            v0 = bz.x; v1 = bz.y; v2 = bz.z; v3 = bz.w;
        } else {
            int kk = k - 3072;
            v0 = selfW[(size_t)(nb + 0) * 512 + kk];
            v1 = selfW[(size_t)(nb + 1) * 512 + kk];
            v2 = selfW[(size_t)(nb + 2) * 512 + kk];
            v3 = selfW[(size_t)(nb + 3) * 512 + kk];
        }
        float vv[4] = {v0, v1, v2, v3};
        for (int i = 0; i < 4; ++i) {
            int n = nb + i;
            wf[(size_t)(k >> 5) * 16384 + (n >> 4) * 512 + ((k >> 3) & 3) * 128 + (n & 15) * 8 + (k & 7)] = f2bf(vv[i]);
        }
    }
}

// ---------------------------------------------------------------------------
// Row masks via coalesced row reads + wave ballot. One wave per (b, r).
__global__ void k_masks(const int* __restrict__ A, u64* __restrict__ m0, u64* __restrict__ m1) {
    int bi = blockIdx.x;          // b*12 + r
    int b = bi / 12, r = bi % 12;
    const int* Ab = A + (size_t)(b * 13 + (r + 1)) * 62 * 62;
    int lane = threadIdx.x;       // 0..63
    u64 my0 = 0, my1 = 0;
    for (int n = 0; n < 64; ++n) {
        int raw = 0;
        if (n < 62 && lane < 62) raw = (Ab[n * 62 + lane] != 0) ? 1 : 0;
        u64 b0 = __ballot(raw != 0);
        int v1 = 0;
        if (n < 63 && lane < 63) {
            int oi = (n == 62) ? 63 : n;
            int oj = (lane == 62) ? 63 : lane;
            v1 = (oi < 62 && oj < 62) ? raw : 0;
            int lo = (oi < oj) ? oi : oj, hi = (oi < oj) ? oj : oi;
            if (hi == lo + 2) {
                int p = (lo >> 1) & 1;
                int chp = ((lo & 1) == 0) ? (p ? 12 : 11) : (p ? 11 : 12);
                if (r + 1 == chp) v1 = 1;
            }
        }
        u64 b1 = __ballot(v1 != 0);
        if (lane == n) { my0 = b0; my1 = b1; }
    }
    m0[(size_t)bi * 64 + lane] = my0;
    m1[(size_t)bi * 64 + lane] = my1;
}

// ---------------------------------------------------------------------------
// Weighted adjacency expansion: A_q = sum_r comb[r][q] * adj_r -> bf16 frags.
#define AQ_SETSTRIDE (256UL * 6 * 4096)
__global__ void k_aqexp(const u64* __restrict__ msk, const float* __restrict__ comb0,
                        const float* __restrict__ comb1, u16* __restrict__ aq) {
    int b = blockIdx.x >> 3, sp = blockIdx.x & 7;
    int t = threadIdx.x;
    __shared__ u64 sm[12 * 64];
    __shared__ float cmb[2][12][6];
    if (t < 72) { cmb[0][t / 6][t % 6] = comb0[t]; cmb[1][t / 6][t % 6] = comb1[t]; }
    for (int i = t; i < 768; i += 256) sm[i] = msk[(size_t)b * 768 + i];
    __syncthreads();
    #pragma unroll
    for (int ii2 = 0; ii2 < 2; ++ii2) {
        int pos = (sp * 2 + ii2) * 256 + t;
        int f = pos >> 9, lane = (pos >> 3) & 63, j = pos & 7;
        int row = ((f >> 1) << 4) + (lane & 15);
        int mb  = ((f & 1) << 5) + ((lane >> 4) << 3) + j;
        float bits[12];
        #pragma unroll
        for (int r = 0; r < 12; ++r) bits[r] = (float)((sm[r * 64 + row] >> mb) & 1ull);
        #pragma unroll
        for (int s = 0; s < 2; ++s)
            #pragma unroll
            for (int q = 0; q < 6; ++q) {
                float v = 0.f;
                #pragma unroll
                for (int r = 0; r < 12; ++r) v += bits[r] * cmb[s][r][q];
                aq[(size_t)s * AQ_SETSTRIDE + ((size_t)b * 6 + q) * 4096 + pos] = f2bf(v);
            }
    }
}

// ---------------------------------------------------------------------------
// initial embedding -> mi1 rows 60..63 ; mi2 rows 62,63  (unchanged, validated)
__global__ void k_prep(const int* __restrict__ player,
                       const float* __restrict__ pAx, const float* __restrict__ pAy,
                       const float* __restrict__ pBx, const float* __restrict__ pBy,
                       const float* __restrict__ emb, const float* __restrict__ cW,
                       const float* __restrict__ cb, const float* __restrict__ inW,
                       const float* __restrict__ inb,
                       u16* __restrict__ mi1, u16* __restrict__ mi2) {
    int b = blockIdx.x, t = threadIdx.x;
    __shared__ float feat[2][64];
    if (t < 64) {
        int j = t >> 5, d = t & 31;
        float X = j ? pBx[b] : pAx[b];
        float Y = j ? pBy[b] : pAy[b];
        feat[j][d] = fmaxf(cW[d * 2] * X + cW[d * 2 + 1] * Y + cb[d], 0.f);
        feat[j][32 + d] = emb[player[b * 2 + j] * 32 + d];
    }
    __syncthreads();
    for (int h = t; h < 512; h += 256) {
        float a0 = inb[h], a1 = inb[h];
        const float* wrow = inW + h * 64;
        #pragma unroll
        for (int d = 0; d < 64; ++d) {
            float wv = wrow[d];
            a0 += wv * feat[0][d];
            a1 += wv * feat[1][d];
        }
        u16 v0 = f2bf(a0), v1 = f2bf(a1);
        size_t base = (size_t)b * 64 * 512;
        mi1[base + 60 * 512 + h] = v0;
        mi1[base + 61 * 512 + h] = v1;
        mi1[base + 62 * 512 + h] = 0;
        mi1[base + 63 * 512 + h] = 0;
        mi2[base + 62 * 512 + h] = v1;
        mi2[base + 63 * 512 + h] = 0;
    }
}

// enc f32 -> mi1 rows 0..59 ; mi2 rows 0..57  (vectorized: float4 x2 -> short8)
__global__ void k_cast(const float* __restrict__ enc, u16* __restrict__ mi1, u16* __restrict__ mi2) {
    long long e = ((long long)blockIdx.x * 256 + threadIdx.x) * 8;
    if (e >= 256LL * 60 * 512) return;
    int b = (int)(e / (60 * 512));
    int rm = (int)(e % (60 * 512));
    int n = rm / 512, h = rm % 512;
    float4 f0 = *(const float4*)(enc + e);
    float4 f1 = *(const float4*)(enc + e + 4);
    short8 pk;
    pk[0] = (short)f2bf(f0.x); pk[1] = (short)f2bf(f0.y);
    pk[2] = (short)f2bf(f0.z); pk[3] = (short)f2bf(f0.w);
    pk[4] = (short)f2bf(f1.x); pk[5] = (short)f2bf(f1.y);
    pk[6] = (short)f2bf(f1.z); pk[7] = (short)f2bf(f1.w);
    *(short8*)(mi1 + ((size_t)b * 64 + n) * 512 + h) = pk;
    if (n < 58) *(short8*)(mi2 + ((size_t)b * 64 + n) * 512 + h) = pk;
}

// ---------------------------------------------------------------------------
// Full RGCN layer via basis decomposition, v11: double-buffered T pipeline.
//   Y = relu( sum_q (A_q @ X) @ B_q  +  X @ selfW^T )
// Block = 1 batch (grid 256 = 1 block/CU), 512 thr = 8 waves; wave w owns
// h-band w*64 in stage A and output col-band w*64 in stage B.
// One barrier per q: iter q = { stageA(q+1)->T[nxt]; stageB(q)<-T[cur]; bar }.
// Self slab runs in the prologue (no T dependency), hiding T[0]'s writes.
__global__ __launch_bounds__(512, 1)
void k_layer(const u16* __restrict__ x, const u16* __restrict__ aq,
             const u16* __restrict__ wc, u16* __restrict__ out) {
    int b = blockIdx.x;
    int t = threadIdx.x, lane = t & 63, w = t >> 6;
    int l15 = lane & 15, lq = lane >> 4;
    const int TS = 520;                      // T row stride (u16), pad vs 512
    __shared__ __align__(16) u16 T[2][64 * 520];   // 133,120 B

    const u16* xb_base = x + (size_t)b * 64 * 512;
    // X as B-operand frags (q-invariant): B[k=j, col=h], h-band = w*64
    short8 xb[8];
    #pragma unroll
    for (int nt = 0; nt < 4; ++nt)
        #pragma unroll
        for (int kh = 0; kh < 2; ++kh) {
            int h = (w * 4 + nt) * 16 + l15;
            int j0 = kh * 32 + lq * 8;
            short8 v;
            #pragma unroll
            for (int jj = 0; jj < 8; ++jj)
                v[jj] = (short)xb_base[(size_t)(j0 + jj) * 512 + h];
            xb[nt * 2 + kh] = v;
        }

    floatx4 acc[16];
    #pragma unroll
    for (int i = 0; i < 16; ++i) acc[i] = (floatx4)(0.f);

    const u16* aqb   = aq + (size_t)b * 6 * 4096 + (size_t)lane * 8;
    const u16* wbase = wc + (size_t)lane * 8;

    // stage A for slab qq into buf (validated round-3 arithmetic)
    auto stageA = [&](int qq, u16* buf) {
        #pragma unroll
        for (int i = 0; i < 4; ++i) {
            short8 a0 = *(const short8*)(aqb + (size_t)qq * 4096 + (i * 2 + 0) * 512);
            short8 a1 = *(const short8*)(aqb + (size_t)qq * 4096 + (i * 2 + 1) * 512);
            #pragma unroll
            for (int nt = 0; nt < 4; ++nt) {
                floatx4 tz = (floatx4)(0.f);
                tz = __builtin_amdgcn_mfma_f32_16x16x32_bf16(a0, xb[nt * 2 + 0], tz, 0, 0, 0);
                tz = __builtin_amdgcn_mfma_f32_16x16x32_bf16(a1, xb[nt * 2 + 1], tz, 0, 0, 0);
                int hcol = (w * 4 + nt) * 16 + l15;
                int mrow = i * 16 + lq * 4;
                #pragma unroll
                for (int reg = 0; reg < 4; ++reg)
                    buf[(mrow + reg) * TS + hcol] = f2bf(tz[reg]);
            }
        }
    };

    // ---- prologue: T[0] writes + self slab (independent of T)
    stageA(0, T[0]);
    for (int ks = 0; ks < 16; ++ks) {
        short8 af[4], bf[4];
        #pragma unroll
        for (int i = 0; i < 4; ++i)
            af[i] = *(const short8*)(xb_base + (size_t)(i * 16 + l15) * 512 + ks * 32 + lq * 8);
        #pragma unroll
        for (int nt = 0; nt < 4; ++nt)
            bf[nt] = *(const short8*)(wbase + (size_t)(96 + ks) * 16384 + (size_t)(w * 4 + nt) * 512);
        #pragma unroll
        for (int i = 0; i < 4; ++i)
            #pragma unroll
            for (int nt = 0; nt < 4; ++nt)
                acc[i * 4 + nt] = __builtin_amdgcn_mfma_f32_16x16x32_bf16(af[i], bf[nt], acc[i * 4 + nt], 0, 0, 0);
    }
    __syncthreads();   // T[0] visible

    // ---- pipelined q loop: one barrier per slab
    for (int q = 0; q < 6; ++q) {
        int cur = q & 1;
        if (q < 5) stageA(q + 1, T[cur ^ 1]);
        // stage B: acc += T_q @ B_q
        for (int ks = 0; ks < 16; ++ks) {
            short8 af[4], bf[4];
            #pragma unroll
            for (int i = 0; i < 4; ++i)
                af[i] = *(const short8*)&T[cur][(i * 16 + l15) * TS + ks * 32 + lq * 8];
            #pragma unroll
            for (int nt = 0; nt < 4; ++nt)
                bf[nt] = *(const short8*)(wbase + (size_t)(q * 16 + ks) * 16384 + (size_t)(w * 4 + nt) * 512);
            #pragma unroll
            for (int i = 0; i < 4; ++i)
                #pragma unroll
                for (int nt = 0; nt < 4; ++nt)
                    acc[i * 4 + nt] = __builtin_amdgcn_mfma_f32_16x16x32_bf16(af[i], bf[nt], acc[i * 4 + nt], 0, 0, 0);
        }
        __syncthreads();   // T[cur] reads done; T[cur^1] writes complete
    }

    // ---- epilogue: relu, y[m = i*16+lq*4+reg][n = (w*4+nt)*16+l15]
    #pragma unroll
    for (int i = 0; i < 4; ++i)
        #pragma unroll
        for (int nt = 0; nt < 4; ++nt) {
            int n = (w * 4 + nt) * 16 + l15;
            int m0 = i * 16 + lq * 4;
            #pragma unroll
            for (int reg = 0; reg < 4; ++reg)
                out[((size_t)b * 64 + m0 + reg) * 512 + n] = f2bf(fmaxf(acc[i * 4 + nt][reg], 0.f));
        }
}

// ---------------------------------------------------------------------------
// Final RGCN layer: only output rows 48..63 needed. v11 pipelined.
__global__ __launch_bounds__(512, 1)
void k_layer_last(const u16* __restrict__ x, const u16* __restrict__ aq,
                  const u16* __restrict__ wc, int mode,
                  u16* __restrict__ o16, float* __restrict__ o32) {
    int b = blockIdx.x;
    int t = threadIdx.x, lane = t & 63, w = t >> 6;
    int l15 = lane & 15, lq = lane >> 4;
    const int TS = 520;
    __shared__ __align__(16) u16 T[2][16 * 520];   // 33,280 B

    const u16* xb_base = x + (size_t)b * 64 * 512;
    short8 xb[8];
    #pragma unroll
    for (int nt = 0; nt < 4; ++nt)
        #pragma unroll
        for (int kh = 0; kh < 2; ++kh) {
            int h = (w * 4 + nt) * 16 + l15;
            int j0 = kh * 32 + lq * 8;
            short8 v;
            #pragma unroll
            for (int jj = 0; jj < 8; ++jj)
                v[jj] = (short)xb_base[(size_t)(j0 + jj) * 512 + h];
            xb[nt * 2 + kh] = v;
        }

    floatx4 acc[4];
    #pragma unroll
    for (int i = 0; i < 4; ++i) acc[i] = (floatx4)(0.f);

    const u16* aqb   = aq + (size_t)b * 6 * 4096 + (size_t)lane * 8;
    const u16* wbase = wc + (size_t)lane * 8;

    auto stageA = [&](int qq, u16* buf) {
        short8 a0 = *(const short8*)(aqb + (size_t)qq * 4096 + 6 * 512);
        short8 a1 = *(const short8*)(aqb + (size_t)qq * 4096 + 7 * 512);
        #pragma unroll
        for (int nt = 0; nt < 4; ++nt) {
            floatx4 tz = (floatx4)(0.f);
            tz = __builtin_amdgcn_mfma_f32_16x16x32_bf16(a0, xb[nt * 2 + 0], tz, 0, 0, 0);
            tz = __builtin_amdgcn_mfma_f32_16x16x32_bf16(a1, xb[nt * 2 + 1], tz, 0, 0, 0);
            int hcol = (w * 4 + nt) * 16 + l15;
            int mrow = lq * 4;
            #pragma unroll
            for (int reg = 0; reg < 4; ++reg)
                buf[(mrow + reg) * TS + hcol] = f2bf(tz[reg]);
        }
    };

    // prologue: T[0] + self slab (X rows 48..63)
    stageA(0, T[0]);
    for (int ks = 0; ks < 16; ++ks) {
        short8 af = *(const short8*)(xb_base + (size_t)(48 + l15) * 512 + ks * 32 + lq * 8);
        #pragma unroll
        for (int nt = 0; nt < 4; ++nt) {
            short8 bf = *(const short8*)(wbase + (size_t)(96 + ks) * 16384 + (size_t)(w * 4 + nt) * 512);
            acc[nt] = __builtin_amdgcn_mfma_f32_16x16x32_bf16(af, bf, acc[nt], 0, 0, 0);
        }
    }
    __syncthreads();

    for (int q = 0; q < 6; ++q) {
        int cur = q & 1;
        if (q < 5) stageA(q + 1, T[cur ^ 1]);
        for (int ks = 0; ks < 16; ++ks) {
            short8 af = *(const short8*)&T[cur][l15 * TS + ks * 32 + lq * 8];
            #pragma unroll
            for (int nt = 0; nt < 4; ++nt) {
                short8 bf = *(const short8*)(wbase + (size_t)(q * 16 + ks) * 16384 + (size_t)(w * 4 + nt) * 512);
                acc[nt] = __builtin_amdgcn_mfma_f32_16x16x32_bf16(af, bf, acc[nt], 0, 0, 0);
            }
        }
        __syncthreads();
    }

    // epilogue: m = 48 + lq*4 + reg, n = (w*4+nt)*16 + l15
    #pragma unroll
    for (int nt = 0; nt < 4; ++nt) {
        int n = (w * 4 + nt) * 16 + l15;
        #pragma unroll
        for (int reg = 0; reg < 4; ++reg) {
            int m = 48 + lq * 4 + reg;
            float v = acc[nt][reg];
            if (mode == 1) {
                if (m >= 58 && m <= 61)
                    o16[((size_t)b * 64 + m) * 512 + n] = f2bf(1.f / (1.f + __expf(-v)));
            } else {
                if (m == 60 || m == 62) {
                    int slot = (m == 60) ? (b * 2) : (b * 2 + 1);
                    o32[(size_t)slot * 512 + n] = 1.f / (1.f + __expf(-v));
                }
            }
        }
    }
}

// logits = [black|white] @ type_W^T + type_b  (unchanged, validated)
__global__ void k_final(const float* __restrict__ t2, const float* __restrict__ tW,
                        const float* __restrict__ tb, float* __restrict__ outp) {
    int b = blockIdx.x, l = threadIdx.x;   // 64 threads
    float a[11];
    #pragma unroll
    for (int j = 0; j < 11; ++j) a[j] = 0.f;
    for (int it = 0; it < 16; ++it) {
        int h = it * 64 + l;
        float c = (h < 512) ? t2[(b * 2 + 1) * 512 + h] : t2[(b * 2 + 0) * 512 + (h - 512)];
        #pragma unroll
        for (int j = 0; j < 11; ++j) a[j] += c * tW[j * 1024 + h];
    }
    #pragma unroll
    for (int j = 0; j < 11; ++j) {
        float v = a[j];
        for (int off = 32; off > 0; off >>= 1) v += __shfl_down(v, off, 64);
        if (l == 0) outp[b * 11 + j] = v + tb[j];
    }
}

// ---------------------------------------------------------------------------
extern "C" void kernel_launch(void* const* d_in, const int* in_sizes, int n_in,
                              void* d_out, int out_size, void* d_ws, size_t ws_size,
                              hipStream_t stream) {
    const int*   player = (const int*)d_in[0];
    const float* enc    = (const float*)d_in[2];
    const int*   adjm   = (const int*)d_in[3];
    const float* pAx    = (const float*)d_in[4];
    const float* pAy    = (const float*)d_in[5];
    const float* pBx    = (const float*)d_in[6];
    const float* pBy    = (const float*)d_in[7];
    const float* emb    = (const float*)d_in[8];
    const float* cW     = (const float*)d_in[9];
    const float* cb     = (const float*)d_in[10];
    const float* inW    = (const float*)d_in[11];
    const float* inb    = (const float*)d_in[12];
    const float* basis0 = (const float*)d_in[13];
    const float* comb0  = (const float*)d_in[14];
    const float* self0  = (const float*)d_in[15];
    const float* basis1 = (const float*)d_in[16];
    const float* comb1  = (const float*)d_in[17];
    const float* self1  = (const float*)d_in[18];
    const float* typeW  = (const float*)d_in[19];
    const float* typeb  = (const float*)d_in[20];

    char* ws = (char*)d_ws;
    size_t off = 0;
    auto alloc = [&](size_t bytes) -> void* {
        void* p = ws + off;
        off = (off + bytes + 255) & ~(size_t)255;
        return p;
    };
    // Workspace (peak ~86.5 MB, under proven 89 MB):
    //   mi1 region: mi1 (prep..layer1) -> x12b (layer3..layer4)
    //   x12 region: x12 (layer1..layer2) -> t2 (layer4..final)
    //   aq region: [set0|set1] variant0 (..layer2) -> variant1 (..layer4)
    u16* mi1   = (u16*)alloc(256UL * 64 * 512 * 2);
    u16* mi2   = (u16*)alloc(256UL * 64 * 512 * 2);
    u16* x12   = (u16*)alloc(256UL * 64 * 512 * 2);
    u16* aqbuf = (u16*)alloc(2UL * AQ_SETSTRIDE * 2);
    u16* wcat0 = (u16*)alloc(3584UL * 512 * 2);
    u16* wcat1 = (u16*)alloc(3584UL * 512 * 2);
    u64* mm0   = (u64*)alloc(256UL * 12 * 64 * 8);
    u64* mm1   = (u64*)alloc(256UL * 12 * 64 * 8);
    u16* x12b  = mi1;             // mi1 dead after layer 1
    float* t2  = (float*)x12;     // x12 dead after layer 2
    u16* aq0   = aqbuf;
    u16* aq1   = aqbuf + AQ_SETSTRIDE;

    k_wcat<<<448, 256, 0, stream>>>(basis0, self0, wcat0);
    k_wcat<<<448, 256, 0, stream>>>(basis1, self1, wcat1);
    k_masks<<<3072, 64, 0, stream>>>(adjm, mm0, mm1);
    k_aqexp<<<2048, 256, 0, stream>>>(mm0, comb0, comb1, aqbuf);
    k_prep<<<256, 256, 0, stream>>>(player, pAx, pAy, pBx, pBy, emb, cW, cb, inW, inb, mi1, mi2);
    k_cast<<<3840, 256, 0, stream>>>(enc, mi1, mi2);

    // rgcn pass 1
    k_layer<<<256, 512, 0, stream>>>(mi1, aq0, wcat0, x12);
    k_layer_last<<<256, 512, 0, stream>>>(x12, aq1, wcat1, 1, mi2, nullptr);
    // regenerate weighted adjacency for the pruned pass-2 graph
    k_aqexp<<<2048, 256, 0, stream>>>(mm1, comb0, comb1, aqbuf);
    // rgcn pass 2
    k_layer<<<256, 512, 0, stream>>>(mi2, aq0, wcat0, x12b);
    k_layer_last<<<256, 512, 0, stream>>>(x12b, aq1, wcat1, 2, nullptr, t2);

    k_final<<<256, 64, 0, stream>>>(t2, typeW, typeb, (float*)d_out);
}

// Round 7
// 694.012 us; speedup vs baseline: 1.0305x; 1.0305x over previous
//
#include <hip/hip_runtime.h>
#include <hip/hip_bf16.h>

typedef unsigned short u16;
typedef unsigned long long u64;
typedef __attribute__((ext_vector_type(4))) short short4v;
typedef __attribute__((ext_vector_type(8))) short short8;
typedef __attribute__((ext_vector_type(4))) float floatx4;

__device__ __forceinline__ u16 f2bf(float f) {
    union { float f; unsigned u; } v; v.f = f;
    unsigned r = v.u + 0x7FFF + ((v.u >> 16) & 1);
    return (u16)(r >> 16);
}

// ---------------------------------------------------------------------------
// Wcat stack: 7 slabs [B_0..B_5, selfW^T], K = 3584, fragment layout validated
// element (k,n) at: (k>>5)*16384 + (n>>4)*512 + ((k>>3)&3)*128 + (n&15)*8 + (k&7)
__global__ void k_wcat(const float* __restrict__ basis, const float* __restrict__ selfW,
                       u16* __restrict__ wf) {
    int bi = blockIdx.x, t = threadIdx.x;
    int kr = t >> 7;             // 0..1
    int nb = (t & 127) * 4;      // n base
    for (int it = 0; it < 4; ++it) {
        int k = bi * 8 + it * 2 + kr;     // 0..3583 over grid 448
        float v0, v1, v2, v3;
        if (k < 3072) {
            int q = k >> 9, h = k & 511;
            const float4 bz = *(const float4*)(basis + ((size_t)(q * 512 + h)) * 512 + nb);
            v0 = bz.x; v1 = bz.y; v2 = bz.z; v3 = bz.w;
        } else {
            int kk = k - 3072;
            v0 = selfW[(size_t)(nb + 0) * 512 + kk];
            v1 = selfW[(size_t)(nb + 1) * 512 + kk];
            v2 = selfW[(size_t)(nb + 2) * 512 + kk];
            v3 = selfW[(size_t)(nb + 3) * 512 + kk];
        }
        float vv[4] = {v0, v1, v2, v3};
        for (int i = 0; i < 4; ++i) {
            int n = nb + i;
            wf[(size_t)(k >> 5) * 16384 + (n >> 4) * 512 + ((k >> 3) & 3) * 128 + (n & 15) * 8 + (k & 7)] = f2bf(vv[i]);
        }
    }
}

// ---------------------------------------------------------------------------
// Row masks via coalesced row reads + wave ballot. One wave per (b, r).
__global__ void k_masks(const int* __restrict__ A, u64* __restrict__ m0, u64* __restrict__ m1) {
    int bi = blockIdx.x;          // b*12 + r
    int b = bi / 12, r = bi % 12;
    const int* Ab = A + (size_t)(b * 13 + (r + 1)) * 62 * 62;
    int lane = threadIdx.x;       // 0..63
    u64 my0 = 0, my1 = 0;
    for (int n = 0; n < 64; ++n) {
        int raw = 0;
        if (n < 62 && lane < 62) raw = (Ab[n * 62 + lane] != 0) ? 1 : 0;
        u64 b0 = __ballot(raw != 0);
        int v1 = 0;
        if (n < 63 && lane < 63) {
            int oi = (n == 62) ? 63 : n;
            int oj = (lane == 62) ? 63 : lane;
            v1 = (oi < 62 && oj < 62) ? raw : 0;
            int lo = (oi < oj) ? oi : oj, hi = (oi < oj) ? oj : oi;
            if (hi == lo + 2) {
                int p = (lo >> 1) & 1;
                int chp = ((lo & 1) == 0) ? (p ? 12 : 11) : (p ? 11 : 12);
                if (r + 1 == chp) v1 = 1;
            }
        }
        u64 b1 = __ballot(v1 != 0);
        if (lane == n) { my0 = b0; my1 = b1; }
    }
    m0[(size_t)bi * 64 + lane] = my0;
    m1[(size_t)bi * 64 + lane] = my1;
}

// ---------------------------------------------------------------------------
// Weighted adjacency expansion: A_q = sum_r comb[r][q] * adj_r -> bf16 frags.
#define AQ_SETSTRIDE (256UL * 6 * 4096)
__global__ void k_aqexp(const u64* __restrict__ msk, const float* __restrict__ comb0,
                        const float* __restrict__ comb1, u16* __restrict__ aq) {
    int b = blockIdx.x >> 3, sp = blockIdx.x & 7;
    int t = threadIdx.x;
    __shared__ u64 sm[12 * 64];
    __shared__ float cmb[2][12][6];
    if (t < 72) { cmb[0][t / 6][t % 6] = comb0[t]; cmb[1][t / 6][t % 6] = comb1[t]; }
    for (int i = t; i < 768; i += 256) sm[i] = msk[(size_t)b * 768 + i];
    __syncthreads();
    #pragma unroll
    for (int ii2 = 0; ii2 < 2; ++ii2) {
        int pos = (sp * 2 + ii2) * 256 + t;
        int f = pos >> 9, lane = (pos >> 3) & 63, j = pos & 7;
        int row = ((f >> 1) << 4) + (lane & 15);
        int mb  = ((f & 1) << 5) + ((lane >> 4) << 3) + j;
        float bits[12];
        #pragma unroll
        for (int r = 0; r < 12; ++r) bits[r] = (float)((sm[r * 64 + row] >> mb) & 1ull);
        #pragma unroll
        for (int s = 0; s < 2; ++s)
            #pragma unroll
            for (int q = 0; q < 6; ++q) {
                float v = 0.f;
                #pragma unroll
                for (int r = 0; r < 12; ++r) v += bits[r] * cmb[s][r][q];
                aq[(size_t)s * AQ_SETSTRIDE + ((size_t)b * 6 + q) * 4096 + pos] = f2bf(v);
            }
    }
}

// ---------------------------------------------------------------------------
// initial embedding -> mi1 rows 60..63 ; mi2 rows 62,63  (unchanged, validated)
__global__ void k_prep(const int* __restrict__ player,
                       const float* __restrict__ pAx, const float* __restrict__ pAy,
                       const float* __restrict__ pBx, const float* __restrict__ pBy,
                       const float* __restrict__ emb, const float* __restrict__ cW,
                       const float* __restrict__ cb, const float* __restrict__ inW,
                       const float* __restrict__ inb,
                       u16* __restrict__ mi1, u16* __restrict__ mi2) {
    int b = blockIdx.x, t = threadIdx.x;
    __shared__ float feat[2][64];
    if (t < 64) {
        int j = t >> 5, d = t & 31;
        float X = j ? pBx[b] : pAx[b];
        float Y = j ? pBy[b] : pAy[b];
        feat[j][d] = fmaxf(cW[d * 2] * X + cW[d * 2 + 1] * Y + cb[d], 0.f);
        feat[j][32 + d] = emb[player[b * 2 + j] * 32 + d];
    }
    __syncthreads();
    for (int h = t; h < 512; h += 256) {
        float a0 = inb[h], a1 = inb[h];
        const float* wrow = inW + h * 64;
        #pragma unroll
        for (int d = 0; d < 64; ++d) {
            float wv = wrow[d];
            a0 += wv * feat[0][d];
            a1 += wv * feat[1][d];
        }
        u16 v0 = f2bf(a0), v1 = f2bf(a1);
        size_t base = (size_t)b * 64 * 512;
        mi1[base + 60 * 512 + h] = v0;
        mi1[base + 61 * 512 + h] = v1;
        mi1[base + 62 * 512 + h] = 0;
        mi1[base + 63 * 512 + h] = 0;
        mi2[base + 62 * 512 + h] = v1;
        mi2[base + 63 * 512 + h] = 0;
    }
}

// enc f32 -> mi1 rows 0..59 ; mi2 rows 0..57  (vectorized, validated round 6)
__global__ void k_cast(const float* __restrict__ enc, u16* __restrict__ mi1, u16* __restrict__ mi2) {
    long long e = ((long long)blockIdx.x * 256 + threadIdx.x) * 8;
    if (e >= 256LL * 60 * 512) return;
    int b = (int)(e / (60 * 512));
    int rm = (int)(e % (60 * 512));
    int n = rm / 512, h = rm % 512;
    float4 f0 = *(const float4*)(enc + e);
    float4 f1 = *(const float4*)(enc + e + 4);
    short8 pk;
    pk[0] = (short)f2bf(f0.x); pk[1] = (short)f2bf(f0.y);
    pk[2] = (short)f2bf(f0.z); pk[3] = (short)f2bf(f0.w);
    pk[4] = (short)f2bf(f1.x); pk[5] = (short)f2bf(f1.y);
    pk[6] = (short)f2bf(f1.z); pk[7] = (short)f2bf(f1.w);
    *(short8*)(mi1 + ((size_t)b * 64 + n) * 512 + h) = pk;
    if (n < 58) *(short8*)(mi2 + ((size_t)b * 64 + n) * 512 + h) = pk;
}

// ---------------------------------------------------------------------------
// Full RGCN layer, v12: block = (batch, col-quarter), 256 thr = 4 waves,
// half-T in LDS (33.8 KB) -> 4 independent blocks/CU (the round-6 lesson:
// latency hiding needs decoupled blocks, not bigger ones).
//   Y = relu( sum_q (A_q @ X) @ B_q  +  X @ selfW^T )
// hh (T h-half) is the OUTER loop so xb (q-invariant) is loaded once per half.
// acc accumulates over (q, hh, ks) in any order (commutative sum over K).
__global__ __launch_bounds__(256, 4)
void k_layer(const u16* __restrict__ x, const u16* __restrict__ aq,
             const u16* __restrict__ wc, u16* __restrict__ out) {
    int b = blockIdx.x >> 2, cq = blockIdx.x & 3;
    int t = threadIdx.x, lane = t & 63, w = t >> 6;   // w 0..3
    int l15 = lane & 15, lq = lane >> 4;
    const int TS = 264;                               // half-T row stride
    __shared__ __align__(16) u16 T[64 * 264];         // 33,792 B

    const u16* xb_base = x + (size_t)b * 64 * 512;
    const u16* aqb   = aq + (size_t)b * 6 * 4096 + (size_t)lane * 8;
    const u16* wbase = wc + (size_t)lane * 8;
    int cf0 = cq * 8 + w * 2;                         // wcat col-frag base (wave: 32 cols)

    floatx4 acc[8];                                   // [i 0..3][nt 0..1]
    #pragma unroll
    for (int i = 0; i < 8; ++i) acc[i] = (floatx4)(0.f);

    // ---- prologue: self slab (af = X rows from global — validated pattern)
    for (int ks = 0; ks < 16; ++ks) {
        short8 af[4], bf[2];
        #pragma unroll
        for (int i = 0; i < 4; ++i)
            af[i] = *(const short8*)(xb_base + (size_t)(i * 16 + l15) * 512 + ks * 32 + lq * 8);
        #pragma unroll
        for (int nt = 0; nt < 2; ++nt)
            bf[nt] = *(const short8*)(wbase + (size_t)(96 + ks) * 16384 + (size_t)(cf0 + nt) * 512);
        #pragma unroll
        for (int i = 0; i < 4; ++i)
            #pragma unroll
            for (int nt = 0; nt < 2; ++nt)
                acc[i * 2 + nt] = __builtin_amdgcn_mfma_f32_16x16x32_bf16(af[i], bf[nt], acc[i * 2 + nt], 0, 0, 0);
    }

    for (int hh = 0; hh < 2; ++hh) {
        // xb for this h-half: B-frags B[k=j, col=h], wave h-band = hh*256 + w*64
        short8 xb[8];
        #pragma unroll
        for (int nt = 0; nt < 4; ++nt)
            #pragma unroll
            for (int kh = 0; kh < 2; ++kh) {
                int h = hh * 256 + w * 64 + nt * 16 + l15;
                int j0 = kh * 32 + lq * 8;
                short8 v;
                #pragma unroll
                for (int jj = 0; jj < 8; ++jj)
                    v[jj] = (short)xb_base[(size_t)(j0 + jj) * 512 + h];
                xb[nt * 2 + kh] = v;
            }

        for (int q = 0; q < 6; ++q) {
            // ---- stage A: T_q[m][h-half hh], wave h-band w*64 (local 0..255)
            #pragma unroll
            for (int i = 0; i < 4; ++i) {
                short8 a0 = *(const short8*)(aqb + (size_t)q * 4096 + (i * 2 + 0) * 512);
                short8 a1 = *(const short8*)(aqb + (size_t)q * 4096 + (i * 2 + 1) * 512);
                #pragma unroll
                for (int nt = 0; nt < 4; ++nt) {
                    floatx4 tz = (floatx4)(0.f);
                    tz = __builtin_amdgcn_mfma_f32_16x16x32_bf16(a0, xb[nt * 2 + 0], tz, 0, 0, 0);
                    tz = __builtin_amdgcn_mfma_f32_16x16x32_bf16(a1, xb[nt * 2 + 1], tz, 0, 0, 0);
                    int hcol = w * 64 + nt * 16 + l15;
                    int mrow = i * 16 + lq * 4;
                    #pragma unroll
                    for (int reg = 0; reg < 4; ++reg)
                        T[(mrow + reg) * TS + hcol] = f2bf(tz[reg]);
                }
            }
            __syncthreads();   // T half visible
            // ---- stage B: acc += T_q(half) @ B_q(half) — wcat ks = q*16 + hh*8 + kk
            for (int kk = 0; kk < 8; ++kk) {
                short8 af[4], bf[2];
                #pragma unroll
                for (int i = 0; i < 4; ++i)
                    af[i] = *(const short8*)&T[(i * 16 + l15) * TS + kk * 32 + lq * 8];
                #pragma unroll
                for (int nt = 0; nt < 2; ++nt)
                    bf[nt] = *(const short8*)(wbase + (size_t)(q * 16 + hh * 8 + kk) * 16384 + (size_t)(cf0 + nt) * 512);
                #pragma unroll
                for (int i = 0; i < 4; ++i)
                    #pragma unroll
                    for (int nt = 0; nt < 2; ++nt)
                        acc[i * 2 + nt] = __builtin_amdgcn_mfma_f32_16x16x32_bf16(af[i], bf[nt], acc[i * 2 + nt], 0, 0, 0);
            }
            __syncthreads();   // T reads done before next stage A overwrites
        }
    }

    // ---- epilogue: relu, y[m = i*16+lq*4+reg][n = cq*128 + w*32 + nt*16 + l15]
    #pragma unroll
    for (int i = 0; i < 4; ++i)
        #pragma unroll
        for (int nt = 0; nt < 2; ++nt) {
            int n = cq * 128 + w * 32 + nt * 16 + l15;
            int m0 = i * 16 + lq * 4;
            #pragma unroll
            for (int reg = 0; reg < 4; ++reg)
                out[((size_t)b * 64 + m0 + reg) * 512 + n] = f2bf(fmaxf(acc[i * 2 + nt][reg], 0.f));
        }
}

// ---------------------------------------------------------------------------
// Final RGCN layer (rows 48..63 only), v12: block = (batch, col-eighth),
// 256 thr = 4 waves, full T (16.6 KB) -> 4+ independent blocks/CU.
__global__ __launch_bounds__(256, 4)
void k_layer_last(const u16* __restrict__ x, const u16* __restrict__ aq,
                  const u16* __restrict__ wc, int mode,
                  u16* __restrict__ o16, float* __restrict__ o32) {
    int b = blockIdx.x >> 3, ce = blockIdx.x & 7;
    int t = threadIdx.x, lane = t & 63, w = t >> 6;   // w 0..3
    int l15 = lane & 15, lq = lane >> 4;
    const int TS = 520;
    __shared__ __align__(16) u16 T[16 * 520];         // 16,640 B

    const u16* xb_base = x + (size_t)b * 64 * 512;
    const u16* aqb   = aq + (size_t)b * 6 * 4096 + (size_t)lane * 8;
    const u16* wbase = wc + (size_t)lane * 8;
    int cf = ce * 4 + w;                              // wave: 16 output cols

    floatx4 acc = (floatx4)(0.f);

    // ---- prologue: self slab (X rows 48..63)
    for (int ks = 0; ks < 16; ++ks) {
        short8 af = *(const short8*)(xb_base + (size_t)(48 + l15) * 512 + ks * 32 + lq * 8);
        short8 bf = *(const short8*)(wbase + (size_t)(96 + ks) * 16384 + (size_t)cf * 512);
        acc = __builtin_amdgcn_mfma_f32_16x16x32_bf16(af, bf, acc, 0, 0, 0);
    }

    // xb: wave h-band = w*128 (8 nt-frags), loaded once (q-invariant)
    short8 xb[16];
    #pragma unroll
    for (int nt = 0; nt < 8; ++nt)
        #pragma unroll
        for (int kh = 0; kh < 2; ++kh) {
            int h = w * 128 + nt * 16 + l15;
            int j0 = kh * 32 + lq * 8;
            short8 v;
            #pragma unroll
            for (int jj = 0; jj < 8; ++jj)
                v[jj] = (short)xb_base[(size_t)(j0 + jj) * 512 + h];
            xb[nt * 2 + kh] = v;
        }

    for (int q = 0; q < 6; ++q) {
        // stage A: rows 48..63 (aq frags 6,7), wave h-band w*128
        short8 a0 = *(const short8*)(aqb + (size_t)q * 4096 + 6 * 512);
        short8 a1 = *(const short8*)(aqb + (size_t)q * 4096 + 7 * 512);
        #pragma unroll
        for (int nt = 0; nt < 8; ++nt) {
            floatx4 tz = (floatx4)(0.f);
            tz = __builtin_amdgcn_mfma_f32_16x16x32_bf16(a0, xb[nt * 2 + 0], tz, 0, 0, 0);
            tz = __builtin_amdgcn_mfma_f32_16x16x32_bf16(a1, xb[nt * 2 + 1], tz, 0, 0, 0);
            int hcol = w * 128 + nt * 16 + l15;
            int mrow = lq * 4;
            #pragma unroll
            for (int reg = 0; reg < 4; ++reg)
                T[(mrow + reg) * TS + hcol] = f2bf(tz[reg]);
        }
        __syncthreads();
        // stage B: wave's 16-col band
        for (int ks = 0; ks < 16; ++ks) {
            short8 af = *(const short8*)&T[l15 * TS + ks * 32 + lq * 8];
            short8 bf = *(const short8*)(wbase + (size_t)(q * 16 + ks) * 16384 + (size_t)cf * 512);
            acc = __builtin_amdgcn_mfma_f32_16x16x32_bf16(af, bf, acc, 0, 0, 0);
        }
        __syncthreads();
    }

    // epilogue: m = 48 + lq*4 + reg, n = ce*64 + w*16 + l15
    int n = ce * 64 + w * 16 + l15;
    #pragma unroll
    for (int reg = 0; reg < 4; ++reg) {
        int m = 48 + lq * 4 + reg;
        float v = acc[reg];
        if (mode == 1) {
            if (m >= 58 && m <= 61)
                o16[((size_t)b * 64 + m) * 512 + n] = f2bf(1.f / (1.f + __expf(-v)));
        } else {
            if (m == 60 || m == 62) {
                int slot = (m == 60) ? (b * 2) : (b * 2 + 1);
                o32[(size_t)slot * 512 + n] = 1.f / (1.f + __expf(-v));
            }
        }
    }
}

// logits = [black|white] @ type_W^T + type_b  (unchanged, validated)
__global__ void k_final(const float* __restrict__ t2, const float* __restrict__ tW,
                        const float* __restrict__ tb, float* __restrict__ outp) {
    int b = blockIdx.x, l = threadIdx.x;   // 64 threads
    float a[11];
    #pragma unroll
    for (int j = 0; j < 11; ++j) a[j] = 0.f;
    for (int it = 0; it < 16; ++it) {
        int h = it * 64 + l;
        float c = (h < 512) ? t2[(b * 2 + 1) * 512 + h] : t2[(b * 2 + 0) * 512 + (h - 512)];
        #pragma unroll
        for (int j = 0; j < 11; ++j) a[j] += c * tW[j * 1024 + h];
    }
    #pragma unroll
    for (int j = 0; j < 11; ++j) {
        float v = a[j];
        for (int off = 32; off > 0; off >>= 1) v += __shfl_down(v, off, 64);
        if (l == 0) outp[b * 11 + j] = v + tb[j];
    }
}

// ---------------------------------------------------------------------------
extern "C" void kernel_launch(void* const* d_in, const int* in_sizes, int n_in,
                              void* d_out, int out_size, void* d_ws, size_t ws_size,
                              hipStream_t stream) {
    const int*   player = (const int*)d_in[0];
    const float* enc    = (const float*)d_in[2];
    const int*   adjm   = (const int*)d_in[3];
    const float* pAx    = (const float*)d_in[4];
    const float* pAy    = (const float*)d_in[5];
    const float* pBx    = (const float*)d_in[6];
    const float* pBy    = (const float*)d_in[7];
    const float* emb    = (const float*)d_in[8];
    const float* cW     = (const float*)d_in[9];
    const float* cb     = (const float*)d_in[10];
    const float* inW    = (const float*)d_in[11];
    const float* inb    = (const float*)d_in[12];
    const float* basis0 = (const float*)d_in[13];
    const float* comb0  = (const float*)d_in[14];
    const float* self0  = (const float*)d_in[15];
    const float* basis1 = (const float*)d_in[16];
    const float* comb1  = (const float*)d_in[17];
    const float* self1  = (const float*)d_in[18];
    const float* typeW  = (const float*)d_in[19];
    const float* typeb  = (const float*)d_in[20];

    char* ws = (char*)d_ws;
    size_t off = 0;
    auto alloc = [&](size_t bytes) -> void* {
        void* p = ws + off;
        off = (off + bytes + 255) & ~(size_t)255;
        return p;
    };
    // Workspace (peak ~86.5 MB, under proven 89 MB):
    //   mi1 region: mi1 (prep..layer1) -> x12b (layer3..layer4)
    //   x12 region: x12 (layer1..layer2) -> t2 (layer4..final)
    //   aq region: [set0|set1] variant0 (..layer2) -> variant1 (..layer4)
    u16* mi1   = (u16*)alloc(256UL * 64 * 512 * 2);
    u16* mi2   = (u16*)alloc(256UL * 64 * 512 * 2);
    u16* x12   = (u16*)alloc(256UL * 64 * 512 * 2);
    u16* aqbuf = (u16*)alloc(2UL * AQ_SETSTRIDE * 2);
    u16* wcat0 = (u16*)alloc(3584UL * 512 * 2);
    u16* wcat1 = (u16*)alloc(3584UL * 512 * 2);
    u64* mm0   = (u64*)alloc(256UL * 12 * 64 * 8);
    u64* mm1   = (u64*)alloc(256UL * 12 * 64 * 8);
    u16* x12b  = mi1;             // mi1 dead after layer 1
    float* t2  = (float*)x12;     // x12 dead after layer 2
    u16* aq0   = aqbuf;
    u16* aq1   = aqbuf + AQ_SETSTRIDE;

    k_wcat<<<448, 256, 0, stream>>>(basis0, self0, wcat0);
    k_wcat<<<448, 256, 0, stream>>>(basis1, self1, wcat1);
    k_masks<<<3072, 64, 0, stream>>>(adjm, mm0, mm1);
    k_aqexp<<<2048, 256, 0, stream>>>(mm0, comb0, comb1, aqbuf);
    k_prep<<<256, 256, 0, stream>>>(player, pAx, pAy, pBx, pBy, emb, cW, cb, inW, inb, mi1, mi2);
    k_cast<<<3840, 256, 0, stream>>>(enc, mi1, mi2);

    // rgcn pass 1
    k_layer<<<1024, 256, 0, stream>>>(mi1, aq0, wcat0, x12);
    k_layer_last<<<2048, 256, 0, stream>>>(x12, aq1, wcat1, 1, mi2, nullptr);
    // regenerate weighted adjacency for the pruned pass-2 graph
    k_aqexp<<<2048, 256, 0, stream>>>(mm1, comb0, comb1, aqbuf);
    // rgcn pass 2
    k_layer<<<1024, 256, 0, stream>>>(mi2, aq0, wcat0, x12b);
    k_layer_last<<<2048, 256, 0, stream>>>(x12b, aq1, wcat1, 2, nullptr, t2);

    k_final<<<256, 64, 0, stream>>>(t2, typeW, typeb, (float*)d_out);
}